// Round 1
// baseline (6292.209 us; speedup 1.0000x reference)
//
#include <hip/hip_runtime.h>

#define NB 131072
#define ND 512
#define NK 64
#define NCB 1024

#define RPB 64              // rows per block
#define ECH 64              // codebook entries per LDS chunk
#define NCH (NCB / ECH)     // 16 chunks
#define ZLD 68              // padded leading dim (68*4 B = 272 = 17*16: float4-aligned rows)

// ---------------------------------------------------------------------------
// Precompute: C_dec[c][d] = sum_k cb[c,k] * U[d,k]   (decoded codebook, 2 MB)
//             c_sq[c]     = ||cb[c]||^2
// (unchanged from the passing kernel)
// ---------------------------------------------------------------------------
__global__ __launch_bounds__(256) void vq_precompute(
    const float* __restrict__ U, const float* __restrict__ cb,
    float* __restrict__ C_dec, float* __restrict__ c_sq)
{
    int t = blockIdx.x * 256 + threadIdx.x;   // 0 .. NCB*ND-1
    int c = t >> 9;                           // uniform within block
    int d = t & (ND - 1);
    const float* __restrict__ crow = cb + (size_t)c * NK;
    const float* __restrict__ urow = U + (size_t)d * NK;
    float a0 = 0.f, a1 = 0.f, a2 = 0.f, a3 = 0.f;
#pragma unroll
    for (int k = 0; k < NK; k += 4) {
        a0 = fmaf(crow[k + 0], urow[k + 0], a0);
        a1 = fmaf(crow[k + 1], urow[k + 1], a1);
        a2 = fmaf(crow[k + 2], urow[k + 2], a2);
        a3 = fmaf(crow[k + 3], urow[k + 3], a3);
    }
    C_dec[t] = (a0 + a1) + (a2 + a3);
    if (d == 0) {
        float s0 = 0.f, s1 = 0.f, s2 = 0.f, s3 = 0.f;
#pragma unroll
        for (int k = 0; k < NK; k += 4) {
            s0 = fmaf(crow[k + 0], crow[k + 0], s0);
            s1 = fmaf(crow[k + 1], crow[k + 1], s1);
            s2 = fmaf(crow[k + 2], crow[k + 2], s2);
            s3 = fmaf(crow[k + 3], crow[k + 3], s3);
        }
        c_sq[c] = (s0 + s1) + (s2 + s3);
    }
}

// ---------------------------------------------------------------------------
// Main kernel v2: cooperative 64-row blocks, register-tiled GEMM phases.
//  Phase A: z[64r][64j], thread tile 4x4; single fmaf chain per (r,j) in
//           ascending d -> bitwise-identical z to the v1 kernel.
//  Phase B: thread tile 4 rows x 4 entries, 4 accumulator chains per pair
//           (k mod 4) -> bitwise-identical distances; cross-lane argmin
//           reduce with index tie-break == serial first-min.
//           Codebook chunks double-buffered in LDS with register prefetch.
//  Phase C: block-wide fully coalesced epilogue writes.
// ---------------------------------------------------------------------------
__global__ __launch_bounds__(256, 3) void vq_main2(
    const float* __restrict__ x, const float* __restrict__ U,
    const float* __restrict__ cb, const float* __restrict__ c_sq,
    const float* __restrict__ C_dec, float* __restrict__ out)
{
    __shared__ __align__(16) float z_lds[RPB][ZLD];        // 17408 B
    __shared__ __align__(16) float cb_lds[2][ECH][ZLD];    // 34816 B
    __shared__ int s_idx[RPB];                             //   256 B

    const int tid = threadIdx.x;
    const int tr  = tid >> 4;          // 16 row-groups of 4
    const int tj  = tid & 15;          // 16 col/entry-groups
    const int r0  = tr << 2;
    const int j0  = tj << 2;
    const size_t rowb = (size_t)blockIdx.x * RPB;

    // ---- chunk-0 codebook prefetch into registers (hides under phase A) ----
    const int se = tid >> 2;           // 0..63: entry within chunk
    const int sq = tid & 3;
    float4 stg[4];
    {
        const float4* s4 = (const float4*)(cb + (size_t)se * NK);
#pragma unroll
        for (int i = 0; i < 4; ++i) stg[i] = s4[i * 4 + sq];
    }

    // ---------------- Phase A: z = x_tile @ U (4x4 register tile) ----------
    float acc[4][4];
#pragma unroll
    for (int a = 0; a < 4; ++a)
#pragma unroll
        for (int b = 0; b < 4; ++b) acc[a][b] = 0.f;

    const float* xp0 = x + (rowb + r0) * ND;
#pragma unroll 2
    for (int d = 0; d < ND; d += 4) {
        float xs[4][4], us[4][4];
#pragma unroll
        for (int rr = 0; rr < 4; ++rr) {
            float4 v = *(const float4*)(xp0 + (size_t)rr * ND + d);
            xs[rr][0] = v.x; xs[rr][1] = v.y; xs[rr][2] = v.z; xs[rr][3] = v.w;
        }
#pragma unroll
        for (int dd = 0; dd < 4; ++dd) {
            float4 v = *(const float4*)(U + (size_t)(d + dd) * NK + j0);
            us[dd][0] = v.x; us[dd][1] = v.y; us[dd][2] = v.z; us[dd][3] = v.w;
        }
        // ascending d, one fmaf per d per (r,j): bitwise == v1's z chain
#pragma unroll
        for (int dd = 0; dd < 4; ++dd)
#pragma unroll
            for (int rr = 0; rr < 4; ++rr)
#pragma unroll
                for (int jj = 0; jj < 4; ++jj)
                    acc[rr][jj] = fmaf(xs[rr][dd], us[dd][jj], acc[rr][jj]);
    }

    // z tile -> LDS (b128 writes)
#pragma unroll
    for (int rr = 0; rr < 4; ++rr) {
        float4 v = make_float4(acc[rr][0], acc[rr][1], acc[rr][2], acc[rr][3]);
        *(float4*)&z_lds[r0 + rr][j0] = v;
    }
    // cb chunk 0 regs -> LDS
#pragma unroll
    for (int i = 0; i < 4; ++i)
        *(float4*)&cb_lds[0][se][i * 16 + sq * 4] = stg[i];
    __syncthreads();

    // ---------------- Phase B: argmin over codebook ------------------------
    float best[4];
    int   bidx[4];
#pragma unroll
    for (int rr = 0; rr < 4; ++rr) { best[rr] = 3.4e38f; bidx[rr] = 0; }

    for (int c = 0; c < NCH; ++c) {
        const int buf = c & 1;
        // issue next chunk's global loads early (latency hides under compute)
        if (c + 1 < NCH) {
            const float4* s4 =
                (const float4*)(cb + ((size_t)(c + 1) * ECH + se) * NK);
#pragma unroll
            for (int i = 0; i < 4; ++i) stg[i] = s4[i * 4 + sq];
        }
        float csq[4];
#pragma unroll
        for (int ee = 0; ee < 4; ++ee) csq[ee] = c_sq[c * ECH + ee * 16 + tj];

        // 4 chains per (row, entry): replicate v1's k%4 accumulators exactly
        float a0[4][4], a1[4][4], a2[4][4], a3[4][4];
#pragma unroll
        for (int rr = 0; rr < 4; ++rr)
#pragma unroll
            for (int ee = 0; ee < 4; ++ee) {
                a0[rr][ee] = 0.f; a1[rr][ee] = 0.f;
                a2[rr][ee] = 0.f; a3[rr][ee] = 0.f;
            }

        for (int k = 0; k < NK; k += 4) {
            float zs[4][4], cs[4][4];
#pragma unroll
            for (int rr = 0; rr < 4; ++rr) {
                float4 v = *(const float4*)&z_lds[r0 + rr][k];
                zs[rr][0] = v.x; zs[rr][1] = v.y; zs[rr][2] = v.z; zs[rr][3] = v.w;
            }
#pragma unroll
            for (int ee = 0; ee < 4; ++ee) {
                float4 v = *(const float4*)&cb_lds[buf][ee * 16 + tj][k];
                cs[ee][0] = v.x; cs[ee][1] = v.y; cs[ee][2] = v.z; cs[ee][3] = v.w;
            }
#pragma unroll
            for (int rr = 0; rr < 4; ++rr)
#pragma unroll
                for (int ee = 0; ee < 4; ++ee) {
                    a0[rr][ee] = fmaf(zs[rr][0], cs[ee][0], a0[rr][ee]);
                    a1[rr][ee] = fmaf(zs[rr][1], cs[ee][1], a1[rr][ee]);
                    a2[rr][ee] = fmaf(zs[rr][2], cs[ee][2], a2[rr][ee]);
                    a3[rr][ee] = fmaf(zs[rr][3], cs[ee][3], a3[rr][ee]);
                }
        }
#pragma unroll
        for (int ee = 0; ee < 4; ++ee)
#pragma unroll
            for (int rr = 0; rr < 4; ++rr) {
                float dot  = (a0[rr][ee] + a1[rr][ee]) + (a2[rr][ee] + a3[rr][ee]);
                float dist = fmaf(-2.f, dot, csq[ee]);   // bitwise == v1
                if (dist < best[rr]) {
                    best[rr] = dist;
                    bidx[rr] = c * ECH + ee * 16 + tj;
                }
            }
        // write prefetched chunk into the other buffer, then one barrier
        if (c + 1 < NCH) {
#pragma unroll
            for (int i = 0; i < 4; ++i)
                *(float4*)&cb_lds[buf ^ 1][se][i * 16 + sq * 4] = stg[i];
        }
        __syncthreads();
    }

    // cross-lane argmin reduce over the 16 entry-threads (same tr group);
    // (min dist, lowest index) == serial first-min since dists are bitwise
#pragma unroll
    for (int rr = 0; rr < 4; ++rr) {
#pragma unroll
        for (int m = 1; m < 16; m <<= 1) {
            float ob = __shfl_xor(best[rr], m);
            int   oi = __shfl_xor(bidx[rr], m);
            if (ob < best[rr] || (ob == best[rr] && oi < bidx[rr])) {
                best[rr] = ob; bidx[rr] = oi;
            }
        }
        if (tj == 0) s_idx[r0 + rr] = bidx[rr];
    }
    __syncthreads();

    // ---------------- Phase C: fully coalesced block-wide epilogue ---------
    float* const out_rec = out;                                   // B*D
    float* const out_z   = out + (size_t)NB * ND;                 // B*K
    float* const out_zq  = out_z + (size_t)NB * NK;               // B*K
    float* const out_idx = out_zq + (size_t)NB * NK;              // B

    if (tid < RPB) out_idx[rowb + tid] = (float)s_idx[tid];

    {   // z: 64 rows * 64 = 16 KB contiguous
        float* dst = out_z + rowb * NK;
#pragma unroll
        for (int i = 0; i < 4; ++i) {
            int off = i * 1024 + tid * 4;
            *(float4*)(dst + off) = *(const float4*)&z_lds[off >> 6][off & 63];
        }
    }
    {   // z_q: gather cb rows (L2-hot), contiguous writes
        float* dst = out_zq + rowb * NK;
#pragma unroll
        for (int i = 0; i < 4; ++i) {
            int off = i * 1024 + tid * 4;
            *(float4*)(dst + off) =
                *(const float4*)(cb + (size_t)s_idx[off >> 6] * NK + (off & 63));
        }
    }
    {   // x_recon: gather C_dec rows (L2-hot), 128 KB contiguous writes
        float* dst = out_rec + rowb * ND;
#pragma unroll 4
        for (int i = 0; i < 32; ++i) {
            int off = i * 1024 + tid * 4;
            *(float4*)(dst + off) =
                *(const float4*)(C_dec + (size_t)s_idx[off >> 9] * ND + (off & 511));
        }
    }
}

// ---------------------------------------------------------------------------
// Fallback (no workspace): v1 monolithic kernel, kept verbatim for safety.
// ---------------------------------------------------------------------------
__global__ __launch_bounds__(256, 2) void vq_main_old(
    const float* __restrict__ x, const float* __restrict__ U,
    const float* __restrict__ cb, float* __restrict__ out)
{
    const int r = blockIdx.x * 256 + threadIdx.x;
    const float4* __restrict__ x4 = (const float4*)(x + (size_t)r * ND);

    float z[NK];
#pragma unroll
    for (int j = 0; j < NK; ++j) z[j] = 0.f;

    for (int k4 = 0; k4 < ND / 4; ++k4) {
        float4 xv = x4[k4];
        const float* __restrict__ u = U + (size_t)(4 * k4) * NK;
#pragma unroll
        for (int j = 0; j < NK; ++j) z[j] = fmaf(u[j], xv.x, z[j]);
        u += NK;
#pragma unroll
        for (int j = 0; j < NK; ++j) z[j] = fmaf(u[j], xv.y, z[j]);
        u += NK;
#pragma unroll
        for (int j = 0; j < NK; ++j) z[j] = fmaf(u[j], xv.z, z[j]);
        u += NK;
#pragma unroll
        for (int j = 0; j < NK; ++j) z[j] = fmaf(u[j], xv.w, z[j]);
    }

    float best = 3.4e38f;
    int bidx = 0;
    for (int j = 0; j < NCB; ++j) {
        const float* __restrict__ c = cb + (size_t)j * NK;
        float a0 = 0.f, a1 = 0.f, a2 = 0.f, a3 = 0.f;
        float s0 = 0.f, s1 = 0.f, s2 = 0.f, s3 = 0.f;
#pragma unroll
        for (int k = 0; k < NK; k += 4) {
            a0 = fmaf(z[k + 0], c[k + 0], a0);
            a1 = fmaf(z[k + 1], c[k + 1], a1);
            a2 = fmaf(z[k + 2], c[k + 2], a2);
            a3 = fmaf(z[k + 3], c[k + 3], a3);
            s0 = fmaf(c[k + 0], c[k + 0], s0);
            s1 = fmaf(c[k + 1], c[k + 1], s1);
            s2 = fmaf(c[k + 2], c[k + 2], s2);
            s3 = fmaf(c[k + 3], c[k + 3], s3);
        }
        float dot = (a0 + a1) + (a2 + a3);
        float csq = (s0 + s1) + (s2 + s3);
        float dist = fmaf(-2.f, dot, csq);
        if (dist < best) { best = dist; bidx = j; }
    }

    float* __restrict__ out_recon = out;
    float* __restrict__ out_z   = out + (size_t)NB * ND;
    float* __restrict__ out_zq  = out_z + (size_t)NB * NK;
    float* __restrict__ out_idx = out_zq + (size_t)NB * NK;

    float4* __restrict__ oz = (float4*)(out_z + (size_t)r * NK);
#pragma unroll
    for (int q = 0; q < NK / 4; ++q)
        oz[q] = make_float4(z[4 * q], z[4 * q + 1], z[4 * q + 2], z[4 * q + 3]);

    float zq[NK];
    const float4* __restrict__ crow4 = (const float4*)(cb + (size_t)bidx * NK);
    float4* __restrict__ ozq = (float4*)(out_zq + (size_t)r * NK);
#pragma unroll
    for (int q = 0; q < NK / 4; ++q) {
        float4 v = crow4[q];
        ozq[q] = v;
        zq[4 * q] = v.x; zq[4 * q + 1] = v.y; zq[4 * q + 2] = v.z; zq[4 * q + 3] = v.w;
    }

    out_idx[r] = (float)bidx;

    float4* __restrict__ orc = (float4*)(out_recon + (size_t)r * ND);
    for (int d = 0; d < ND; d += 4) {
        float r0 = 0.f, r1 = 0.f, r2 = 0.f, r3 = 0.f;
        const float* __restrict__ u0 = U + (size_t)(d + 0) * NK;
        const float* __restrict__ u1 = U + (size_t)(d + 1) * NK;
        const float* __restrict__ u2 = U + (size_t)(d + 2) * NK;
        const float* __restrict__ u3 = U + (size_t)(d + 3) * NK;
#pragma unroll
        for (int k = 0; k < NK; ++k) {
            r0 = fmaf(zq[k], u0[k], r0);
            r1 = fmaf(zq[k], u1[k], r1);
            r2 = fmaf(zq[k], u2[k], r2);
            r3 = fmaf(zq[k], u3[k], r3);
        }
        orc[d / 4] = make_float4(r0, r1, r2, r3);
    }
}

extern "C" void kernel_launch(void* const* d_in, const int* in_sizes, int n_in,
                              void* d_out, int out_size, void* d_ws, size_t ws_size,
                              hipStream_t stream) {
    const float* x  = (const float*)d_in[0];
    const float* U  = (const float*)d_in[1];
    const float* cb = (const float*)d_in[2];
    float* out = (float*)d_out;

    const size_t need = (size_t)NCB * ND * sizeof(float) + NCB * sizeof(float);
    if (ws_size >= need) {
        float* C_dec = (float*)d_ws;
        float* c_sq  = C_dec + (size_t)NCB * ND;
        vq_precompute<<<(NCB * ND) / 256, 256, 0, stream>>>(U, cb, C_dec, c_sq);
        vq_main2<<<NB / RPB, 256, 0, stream>>>(x, U, cb, c_sq, C_dec, out);
    } else {
        vq_main_old<<<NB / 256, 256, 0, stream>>>(x, U, cb, out);
    }
}

// Round 2
// 1295.742 us; speedup vs baseline: 4.8561x; 4.8561x over previous
//
#include <hip/hip_runtime.h>

#define NB 131072
#define ND 512
#define NK 64
#define NCB 1024

#define TPB 256
#define RPB2 128            // rows per block (2 threads per row)
#define CHF 4096            // floats per 16 KB chunk (64 rows/entries x 64)

// ---------------------------------------------------------------------------
// Precompute: C_dec[c][d] = sum_k cb[c,k] * U[d,k]   (decoded codebook, 2 MB)
//             c_sq[c]     = ||cb[c]||^2
// (unchanged from the passing kernel)
// ---------------------------------------------------------------------------
__global__ __launch_bounds__(256) void vq_precompute(
    const float* __restrict__ U, const float* __restrict__ cb,
    float* __restrict__ C_dec, float* __restrict__ c_sq)
{
    int t = blockIdx.x * 256 + threadIdx.x;   // 0 .. NCB*ND-1
    int c = t >> 9;                           // uniform within block
    int d = t & (ND - 1);
    const float* __restrict__ crow = cb + (size_t)c * NK;
    const float* __restrict__ urow = U + (size_t)d * NK;
    float a0 = 0.f, a1 = 0.f, a2 = 0.f, a3 = 0.f;
#pragma unroll
    for (int k = 0; k < NK; k += 4) {
        a0 = fmaf(crow[k + 0], urow[k + 0], a0);
        a1 = fmaf(crow[k + 1], urow[k + 1], a1);
        a2 = fmaf(crow[k + 2], urow[k + 2], a2);
        a3 = fmaf(crow[k + 3], urow[k + 3], a3);
    }
    C_dec[t] = (a0 + a1) + (a2 + a3);
    if (d == 0) {
        float s0 = 0.f, s1 = 0.f, s2 = 0.f, s3 = 0.f;
#pragma unroll
        for (int k = 0; k < NK; k += 4) {
            s0 = fmaf(crow[k + 0], crow[k + 0], s0);
            s1 = fmaf(crow[k + 1], crow[k + 1], s1);
            s2 = fmaf(crow[k + 2], crow[k + 2], s2);
            s3 = fmaf(crow[k + 3], crow[k + 3], s3);
        }
        c_sq[c] = (s0 + s1) + (s2 + s3);
    }
}

// ---------------------------------------------------------------------------
// Main v3: 128 rows/block, 2 threads per row. z stays in VGPRs (v1-proven).
//   A-threads (tid<128): phase A compute z for row rowb+tid, publish via
//     out_z; phase B scans entries 0..31 of each chunk.
//   B-threads (tid>=128): stage U/cb chunks during phase A (idle otherwise),
//     pick up z from out_z; phase B scans entries 32..63 of each chunk.
//   cb chunks double-buffered in LDS, read as wave-uniform broadcasts
//   (conflict-free). All arithmetic bitwise-identical to v1; pair-combine
//   (min dist, min index) == serial first-min.
// ---------------------------------------------------------------------------
__global__ __launch_bounds__(256, 2) void vq_main3(
    const float* __restrict__ x, const float* __restrict__ U,
    const float* __restrict__ cb, const float* __restrict__ c_sq,
    const float* __restrict__ C_dec, float* __restrict__ out)
{
    __shared__ __align__(16) float buf[2][CHF];   // 32 KB staging, dbuf
    __shared__ float csq_lds[NCB];                // 4 KB
    __shared__ float s_d[TPB];                    // 1 KB
    __shared__ int   s_j[TPB];                    // 1 KB
    __shared__ int   s_idx[RPB2];                 // 0.5 KB

    const int tid = threadIdx.x;
    const size_t rowb = (size_t)blockIdx.x * RPB2;

    float* const out_rec = out;                                   // B*D
    float* const out_z   = out + (size_t)NB * ND;                 // B*K
    float* const out_zq  = out_z + (size_t)NB * NK;               // B*K
    float* const out_idx = out_zq + (size_t)NB * NK;              // B

    // ---- prologue: stage c_sq and U chunk 0 ----
#pragma unroll
    for (int i = 0; i < 4; ++i) csq_lds[i * 256 + tid] = c_sq[i * 256 + tid];
    {
        const float4* s4 = (const float4*)U;
        float4* d4 = (float4*)&buf[0][0];
        float4 t0 = s4[0 * 256 + tid], t1 = s4[1 * 256 + tid],
               t2 = s4[2 * 256 + tid], t3 = s4[3 * 256 + tid];
        d4[0 * 256 + tid] = t0; d4[1 * 256 + tid] = t1;
        d4[2 * 256 + tid] = t2; d4[3 * 256 + tid] = t3;
    }
    __syncthreads();

    float z[NK];
#pragma unroll
    for (int j = 0; j < NK; ++j) z[j] = 0.f;

    // ---- phase A: A-threads compute z (U broadcast from LDS);
    //      B-threads stage next U chunk (dc<7) / cb chunk 0 (dc==7) ----
    for (int dc = 0; dc < 8; ++dc) {
        const int cur = dc & 1;
        if (tid >= 128) {
            const int tB = tid - 128;
            const float4* s4 =
                (const float4*)((dc < 7) ? (U + (size_t)(dc + 1) * CHF) : cb);
            float4* d4 = (float4*)&buf[cur ^ 1][0];
#pragma unroll
            for (int h = 0; h < 2; ++h) {
                float4 t0 = s4[(h * 4 + 0) * 128 + tB];
                float4 t1 = s4[(h * 4 + 1) * 128 + tB];
                float4 t2 = s4[(h * 4 + 2) * 128 + tB];
                float4 t3 = s4[(h * 4 + 3) * 128 + tB];
                d4[(h * 4 + 0) * 128 + tB] = t0;
                d4[(h * 4 + 1) * 128 + tB] = t1;
                d4[(h * 4 + 2) * 128 + tB] = t2;
                d4[(h * 4 + 3) * 128 + tB] = t3;
            }
        } else {
            const float* bufc = &buf[cur][0];
            const float4* x4 = (const float4*)(x + (rowb + tid) * ND);
#pragma unroll 2
            for (int k4 = 0; k4 < 16; ++k4) {
                float4 xv = x4[dc * 16 + k4];
                float xc[4] = {xv.x, xv.y, xv.z, xv.w};
                const float* u = bufc + k4 * 4 * NK;
                // ascending d, ascending j: bitwise == v1's z chain
#pragma unroll
                for (int dd = 0; dd < 4; ++dd) {
#pragma unroll
                    for (int q = 0; q < 16; ++q) {
                        float4 uv = *(const float4*)(u + 4 * q);
                        z[4 * q + 0] = fmaf(uv.x, xc[dd], z[4 * q + 0]);
                        z[4 * q + 1] = fmaf(uv.y, xc[dd], z[4 * q + 1]);
                        z[4 * q + 2] = fmaf(uv.z, xc[dd], z[4 * q + 2]);
                        z[4 * q + 3] = fmaf(uv.w, xc[dd], z[4 * q + 3]);
                    }
                    u += NK;
                }
            }
        }
        __syncthreads();
    }

    // ---- A publishes z (this IS the z output); B picks it up bit-exactly ----
    if (tid < 128) {
        float4* zd = (float4*)(out_z + (rowb + tid) * NK);
#pragma unroll
        for (int q = 0; q < 16; ++q)
            zd[q] = make_float4(z[4 * q], z[4 * q + 1], z[4 * q + 2], z[4 * q + 3]);
    }
    __syncthreads();   // drains vmcnt; same block -> same CU/L2: reads are safe
    if (tid >= 128) {
        const float4* zs = (const float4*)(out_z + (rowb + tid - 128) * NK);
#pragma unroll
        for (int q = 0; q < 16; ++q) {
            float4 v = zs[q];
            z[4 * q + 0] = v.x; z[4 * q + 1] = v.y;
            z[4 * q + 2] = v.z; z[4 * q + 3] = v.w;
        }
    }

    // ---- phase B: each half-thread scans 32 entries/chunk, LDS broadcast ----
    const int e0 = (tid < 128) ? 0 : 32;
    float best = 3.4e38f;
    int bidx = 0;
    for (int c = 0; c < 16; ++c) {
        const int cur = c & 1;
        float4 p0, p1, p2, p3;
        if (c < 15) {   // issue next chunk's loads early (T14)
            const float4* s4 = (const float4*)(cb + (size_t)(c + 1) * CHF);
            p0 = s4[0 * 256 + tid]; p1 = s4[1 * 256 + tid];
            p2 = s4[2 * 256 + tid]; p3 = s4[3 * 256 + tid];
        }
        const float* bufc = &buf[cur][0];
#pragma unroll 2
        for (int e = e0; e < e0 + 32; ++e) {
            const float* crow = bufc + e * NK;   // wave-uniform -> broadcast
            float a0 = 0.f, a1 = 0.f, a2 = 0.f, a3 = 0.f;
#pragma unroll
            for (int k = 0; k < NK; k += 4) {
                float4 cv = *(const float4*)(crow + k);
                a0 = fmaf(z[k + 0], cv.x, a0);
                a1 = fmaf(z[k + 1], cv.y, a1);
                a2 = fmaf(z[k + 2], cv.z, a2);
                a3 = fmaf(z[k + 3], cv.w, a3);
            }
            float dot = (a0 + a1) + (a2 + a3);
            int j = c * 64 + e;
            float dist = fmaf(-2.f, dot, csq_lds[j]);   // bitwise == v1
            if (dist < best) { best = dist; bidx = j; } // strict < == first-min
        }
        if (c < 15) {   // write-late into the other buffer
            float4* d4 = (float4*)&buf[cur ^ 1][0];
            d4[0 * 256 + tid] = p0; d4[1 * 256 + tid] = p1;
            d4[2 * 256 + tid] = p2; d4[3 * 256 + tid] = p3;
        }
        __syncthreads();
    }

    // ---- combine the two half-scans: (min dist, min index) == serial scan ----
    s_d[tid] = best; s_j[tid] = bidx;
    __syncthreads();
    if (tid < 128) {
        float dB = s_d[tid + 128]; int jB = s_j[tid + 128];
        int take = (dB < best) || (dB == best && jB < bidx);
        int j = take ? jB : bidx;
        s_idx[tid] = j;
        out_idx[rowb + tid] = (float)j;
    }
    __syncthreads();

    // ---- phase C: fully coalesced gathers ----
    {   // z_q: 128 rows * 64 = 32 KB contiguous writes, cb rows L2-hot
        float* dst = out_zq + rowb * NK;
#pragma unroll
        for (int i = 0; i < 8; ++i) {
            int off = i * 1024 + tid * 4;
            *(float4*)(dst + off) =
                *(const float4*)(cb + (size_t)s_idx[off >> 6] * NK + (off & 63));
        }
    }
    {   // x_recon: 128 rows * 512 = 256 KB contiguous writes, C_dec L2-hot
        float* dst = out_rec + rowb * ND;
#pragma unroll 4
        for (int i = 0; i < 64; ++i) {
            int off = i * 1024 + tid * 4;
            *(float4*)(dst + off) =
                *(const float4*)(C_dec + (size_t)s_idx[off >> 9] * ND + (off & 511));
        }
    }
}

// ---------------------------------------------------------------------------
// Fallback (no workspace): v1 monolithic kernel, kept verbatim for safety.
// ---------------------------------------------------------------------------
__global__ __launch_bounds__(256, 2) void vq_main_old(
    const float* __restrict__ x, const float* __restrict__ U,
    const float* __restrict__ cb, float* __restrict__ out)
{
    const int r = blockIdx.x * 256 + threadIdx.x;
    const float4* __restrict__ x4 = (const float4*)(x + (size_t)r * ND);

    float z[NK];
#pragma unroll
    for (int j = 0; j < NK; ++j) z[j] = 0.f;

    for (int k4 = 0; k4 < ND / 4; ++k4) {
        float4 xv = x4[k4];
        const float* __restrict__ u = U + (size_t)(4 * k4) * NK;
#pragma unroll
        for (int j = 0; j < NK; ++j) z[j] = fmaf(u[j], xv.x, z[j]);
        u += NK;
#pragma unroll
        for (int j = 0; j < NK; ++j) z[j] = fmaf(u[j], xv.y, z[j]);
        u += NK;
#pragma unroll
        for (int j = 0; j < NK; ++j) z[j] = fmaf(u[j], xv.z, z[j]);
        u += NK;
#pragma unroll
        for (int j = 0; j < NK; ++j) z[j] = fmaf(u[j], xv.w, z[j]);
    }

    float best = 3.4e38f;
    int bidx = 0;
    for (int j = 0; j < NCB; ++j) {
        const float* __restrict__ c = cb + (size_t)j * NK;
        float a0 = 0.f, a1 = 0.f, a2 = 0.f, a3 = 0.f;
        float s0 = 0.f, s1 = 0.f, s2 = 0.f, s3 = 0.f;
#pragma unroll
        for (int k = 0; k < NK; k += 4) {
            a0 = fmaf(z[k + 0], c[k + 0], a0);
            a1 = fmaf(z[k + 1], c[k + 1], a1);
            a2 = fmaf(z[k + 2], c[k + 2], a2);
            a3 = fmaf(z[k + 3], c[k + 3], a3);
            s0 = fmaf(c[k + 0], c[k + 0], s0);
            s1 = fmaf(c[k + 1], c[k + 1], s1);
            s2 = fmaf(c[k + 2], c[k + 2], s2);
            s3 = fmaf(c[k + 3], c[k + 3], s3);
        }
        float dot = (a0 + a1) + (a2 + a3);
        float csq = (s0 + s1) + (s2 + s3);
        float dist = fmaf(-2.f, dot, csq);
        if (dist < best) { best = dist; bidx = j; }
    }

    float* __restrict__ out_recon = out;
    float* __restrict__ out_z   = out + (size_t)NB * ND;
    float* __restrict__ out_zq  = out_z + (size_t)NB * NK;
    float* __restrict__ out_idx = out_zq + (size_t)NB * NK;

    float4* __restrict__ oz = (float4*)(out_z + (size_t)r * NK);
#pragma unroll
    for (int q = 0; q < NK / 4; ++q)
        oz[q] = make_float4(z[4 * q], z[4 * q + 1], z[4 * q + 2], z[4 * q + 3]);

    float zq[NK];
    const float4* __restrict__ crow4 = (const float4*)(cb + (size_t)bidx * NK);
    float4* __restrict__ ozq = (float4*)(out_zq + (size_t)r * NK);
#pragma unroll
    for (int q = 0; q < NK / 4; ++q) {
        float4 v = crow4[q];
        ozq[q] = v;
        zq[4 * q] = v.x; zq[4 * q + 1] = v.y; zq[4 * q + 2] = v.z; zq[4 * q + 3] = v.w;
    }

    out_idx[r] = (float)bidx;

    float4* __restrict__ orc = (float4*)(out_recon + (size_t)r * ND);
    for (int d = 0; d < ND; d += 4) {
        float r0 = 0.f, r1 = 0.f, r2 = 0.f, r3 = 0.f;
        const float* __restrict__ u0 = U + (size_t)(d + 0) * NK;
        const float* __restrict__ u1 = U + (size_t)(d + 1) * NK;
        const float* __restrict__ u2 = U + (size_t)(d + 2) * NK;
        const float* __restrict__ u3 = U + (size_t)(d + 3) * NK;
#pragma unroll
        for (int k = 0; k < NK; ++k) {
            r0 = fmaf(zq[k], u0[k], r0);
            r1 = fmaf(zq[k], u1[k], r1);
            r2 = fmaf(zq[k], u2[k], r2);
            r3 = fmaf(zq[k], u3[k], r3);
        }
        orc[d / 4] = make_float4(r0, r1, r2, r3);
    }
}

extern "C" void kernel_launch(void* const* d_in, const int* in_sizes, int n_in,
                              void* d_out, int out_size, void* d_ws, size_t ws_size,
                              hipStream_t stream) {
    const float* x  = (const float*)d_in[0];
    const float* U  = (const float*)d_in[1];
    const float* cb = (const float*)d_in[2];
    float* out = (float*)d_out;

    const size_t need = (size_t)NCB * ND * sizeof(float) + NCB * sizeof(float);
    if (ws_size >= need) {
        float* C_dec = (float*)d_ws;
        float* c_sq  = C_dec + (size_t)NCB * ND;
        vq_precompute<<<(NCB * ND) / 256, 256, 0, stream>>>(U, cb, C_dec, c_sq);
        vq_main3<<<NB / RPB2, TPB, 0, stream>>>(x, U, cb, c_sq, C_dec, out);
    } else {
        vq_main_old<<<NB / 256, 256, 0, stream>>>(x, U, cb, out);
    }
}